// Round 17
// baseline (2093.616 us; speedup 1.0000x reference)
//
#include <hip/hip_runtime.h>
#include <hip/hip_bf16.h>

// Problem constants
#define Hn 16
#define Dm 1024
#define HDm 64
#define Tn 1024
#define NT 2048      // B*T
#define Ln 8
#define Vn 32000
#define DFF 4096

typedef unsigned short u16;
typedef unsigned short ushort8 __attribute__((ext_vector_type(8)));
typedef __bf16 bf16x8 __attribute__((ext_vector_type(8)));
typedef float f32x4 __attribute__((ext_vector_type(4)));

__device__ __forceinline__ float b2f(u16 u) {
    union { unsigned int i; float f; } x; x.i = ((unsigned int)u) << 16; return x.f;
}
__device__ __forceinline__ u16 f2b(float f) {
    union { float f; unsigned int i; } x; x.f = f;
    unsigned int r = x.i + 0x7FFFu + ((x.i >> 16) & 1u);
    return (u16)(r >> 16);
}
__device__ __forceinline__ float inload(const void* p, size_t idx, bool isBf) {
    return isBf ? b2f(((const u16*)p)[idx]) : ((const float*)p)[idx];
}

// global -> LDS direct copy, 16B per lane. LDS dest must be the wave-uniform base;
// HW adds lane*16. Low 32 bits of a generic LDS address = DS offset (verified r4).
__device__ __forceinline__ void gload16(const void* g, void* l) {
    const unsigned int __attribute__((address_space(1)))* gp =
        (const unsigned int __attribute__((address_space(1)))*)(unsigned long long)g;
    unsigned int __attribute__((address_space(3)))* lp =
        (unsigned int __attribute__((address_space(3)))*)(unsigned int)(unsigned long long)l;
    __builtin_amdgcn_global_load_lds(gp, lp, 16, 0, 0);
}

// ---------------- dtype sniffer ---------------------------------------------------
__global__ __launch_bounds__(256) void sniff_k(const void* temb, int* flag)
{
    int tid = threadIdx.x;
    const u16* p = (const u16*)temb;
    int cnt = 0;
    for (int i = tid; i < 4096; i += 256) {
        float v = b2f(p[2 * i]);
        if (!(fabsf(v) < 8.0f)) cnt++;
    }
    __shared__ int red[256];
    red[tid] = cnt;
    __syncthreads();
    for (int st = 128; st > 0; st >>= 1) {
        if (tid < st) red[tid] += red[tid + st];
        __syncthreads();
    }
    if (tid == 0) flag[0] = (red[0] < 8) ? 1 : 0;   // 1 = bf16, 0 = f32
}

// ---------------- weight f32 -> bf16 preconversion (single region) ---------------
__global__ __launch_bounds__(256) void conv_k(
    const void* __restrict__ src, u16* __restrict__ dst, const int* __restrict__ flagp)
{
    if (flagp[0] != 0) return;
    size_t i = ((size_t)blockIdx.x * 256 + threadIdx.x) * 8;
    const float* s = (const float*)src + i;
    f32x4 a = *(const f32x4*)s;
    f32x4 b = *(const f32x4*)(s + 4);
    ushort8 o;
    o[0]=f2b(a[0]); o[1]=f2b(a[1]); o[2]=f2b(a[2]); o[3]=f2b(a[3]);
    o[4]=f2b(b[0]); o[5]=f2b(b[1]); o[6]=f2b(b[2]); o[7]=f2b(b[3]);
    *(ushort8*)(dst + i) = o;
}

// ---------------- merged 5-region preconversion (one launch, r17) ----------------
// Block counts (2048 elems/block): LM 16000 | QKV 12288 | OUT 4096 | W1 16384 |
// W2 16384 -> total 65152.
__global__ __launch_bounds__(256) void conv5_k(
    const void* __restrict__ s0, u16* __restrict__ d0,
    const void* __restrict__ s1, u16* __restrict__ d1,
    const void* __restrict__ s2, u16* __restrict__ d2,
    const void* __restrict__ s3, u16* __restrict__ d3,
    const void* __restrict__ s4, u16* __restrict__ d4,
    const int* __restrict__ flagp)
{
    if (flagp[0] != 0) return;
    const int bid = blockIdx.x;
    const float* s; u16* d; int base;
    if      (bid < 16000) { s = (const float*)s0; d = d0; base = bid; }
    else if (bid < 28288) { s = (const float*)s1; d = d1; base = bid - 16000; }
    else if (bid < 32384) { s = (const float*)s2; d = d2; base = bid - 28288; }
    else if (bid < 48768) { s = (const float*)s3; d = d3; base = bid - 32384; }
    else                  { s = (const float*)s4; d = d4; base = bid - 48768; }
    size_t i = ((size_t)base * 256 + threadIdx.x) * 8;
    f32x4 a = *(const f32x4*)(s + i);
    f32x4 b = *(const f32x4*)(s + i + 4);
    ushort8 o;
    o[0]=f2b(a[0]); o[1]=f2b(a[1]); o[2]=f2b(a[2]); o[3]=f2b(a[3]);
    o[4]=f2b(b[0]); o[5]=f2b(b[1]); o[6]=f2b(b[2]); o[7]=f2b(b[3]);
    *(ushort8*)(d + i) = o;
}

// ---------------- embed ----------------------------------------------------------
__global__ __launch_bounds__(256) void embed_k(
    const int* __restrict__ ids, const void* __restrict__ temb,
    const void* __restrict__ pemb, float* __restrict__ x,
    const int* __restrict__ flagp)
{
    const bool isBf = flagp[0] != 0;
    int n = blockIdx.x;
    int t = n & (Tn - 1);
    int id = ids[n];
    int d = threadIdx.x * 4;
    float* xo = x + (size_t)n * Dm + d;
#pragma unroll
    for (int j = 0; j < 4; ++j)
        xo[j] = inload(temb, (size_t)id * Dm + d + j, isBf)
              + inload(pemb, (size_t)t  * Dm + d + j, isBf);
}

// ---------------- legacy layernorm (fallback tiers) ------------------------------
__global__ __launch_bounds__(256) void ln_k(
    const float* __restrict__ x, const void* __restrict__ g,
    const void* __restrict__ bta, size_t goff, u16* __restrict__ hout,
    const int* __restrict__ flagp)
{
    const bool isBf = flagp[0] != 0;
    int n = blockIdx.x;
    int tid = threadIdx.x;
    const float* xr = x + (size_t)n * Dm;
    f32x4 v = *(const f32x4*)&xr[tid * 4];
    float s = v[0] + v[1] + v[2] + v[3];
    float ss = v[0]*v[0] + v[1]*v[1] + v[2]*v[2] + v[3]*v[3];
    __shared__ float r1[256], r2[256];
    r1[tid] = s; r2[tid] = ss;
    __syncthreads();
    for (int st = 128; st > 0; st >>= 1) {
        if (tid < st) { r1[tid] += r1[tid + st]; r2[tid] += r2[tid + st]; }
        __syncthreads();
    }
    float mean = r1[0] * (1.0f / Dm);
    float var  = r2[0] * (1.0f / Dm) - mean * mean;
    float rs = rsqrtf(var + 1e-5f);
    u16* ho = hout + (size_t)n * Dm + tid * 4;
#pragma unroll
    for (int j = 0; j < 4; ++j) {
        float gv = inload(g,   goff + tid * 4 + j, isBf);
        float bv = inload(bta, goff + tid * 4 + j, isBf);
        ho[j] = f2b((v[j] - mean) * rs * gv + bv);
    }
}

// ---------------- fused: x += P0+P1; h = LN(x)*g+b  (nP = 0 or 2) ----------------
__global__ __launch_bounds__(256) void lnfuse_k(
    float* __restrict__ x, const float* __restrict__ P, int nP,
    const void* __restrict__ g, const void* __restrict__ bta, size_t goff,
    u16* __restrict__ hout, const int* __restrict__ flagp)
{
    const bool isBf = flagp[0] != 0;
    int n = blockIdx.x;
    int tid = threadIdx.x;
    float* xr = x + (size_t)n * Dm;
    f32x4 v = *(const f32x4*)&xr[tid * 4];
    if (nP == 2) {
        const float* p0 = P + (size_t)n * Dm;
        const float* p1 = P + (size_t)NT * Dm + (size_t)n * Dm;
        f32x4 a = *(const f32x4*)&p0[tid * 4];
        f32x4 b = *(const f32x4*)&p1[tid * 4];
#pragma unroll
        for (int j = 0; j < 4; ++j) v[j] = v[j] + a[j] + b[j];
        *(f32x4*)&xr[tid * 4] = v;          // write back residual stream
    }
    float s = v[0] + v[1] + v[2] + v[3];
    float ss = v[0]*v[0] + v[1]*v[1] + v[2]*v[2] + v[3]*v[3];
    __shared__ float r1[256], r2[256];
    r1[tid] = s; r2[tid] = ss;
    __syncthreads();
    for (int st = 128; st > 0; st >>= 1) {
        if (tid < st) { r1[tid] += r1[tid + st]; r2[tid] += r2[tid + st]; }
        __syncthreads();
    }
    float mean = r1[0] * (1.0f / Dm);
    float var  = r2[0] * (1.0f / Dm) - mean * mean;
    float rs = rsqrtf(var + 1e-5f);
    u16* ho = hout + (size_t)n * Dm + tid * 4;
#pragma unroll
    for (int j = 0; j < 4; ++j) {
        float gv = inload(g,   goff + tid * 4 + j, isBf);
        float bv = inload(bta, goff + tid * 4 + j, isBf);
        ho[j] = f2b((v[j] - mean) * rs * gv + bv);
    }
}

// ---------------- legacy dual-dtype MFMA GEMM (fallback path) --------------------
template<int EPI>
__global__ __launch_bounds__(256) void gemm_k(
    const u16* __restrict__ A, const void* __restrict__ Bw, size_t woff,
    const void* __restrict__ bias, size_t boff,
    u16* __restrict__ Obf, float* __restrict__ Xres, void* __restrict__ Oext,
    const int* __restrict__ flagp, int M, int N, int K)
{
    const bool isBf = flagp[0] != 0;
    __shared__ __align__(16) u16 As[128][40];
    __shared__ __align__(16) u16 Bs[128][40];
    const int tid  = threadIdx.x;
    const int lane = tid & 63;
    const int wave = tid >> 6;
    const int wr = (wave >> 1) * 64;
    const int wc = (wave & 1) * 64;
    const int row0 = blockIdx.y * 128;
    const int col0 = blockIdx.x * 128;
    const int lr = lane & 15;
    const int lk = (lane >> 4) * 8;
    const int sr = tid >> 2;
    const int sc = (tid & 3) * 8;

    f32x4 acc[4][4] = {};

    for (int k0 = 0; k0 < K; k0 += 32) {
#pragma unroll
        for (int i = 0; i < 2; ++i) {
            int r = sr + i * 64;
            *(ushort8*)&As[r][sc] = *(const ushort8*)&A[(size_t)(row0 + r) * K + k0 + sc];
            size_t be = woff + (size_t)(col0 + r) * K + k0 + sc;
            if (isBf) {
                *(ushort8*)&Bs[r][sc] = *(const ushort8*)&((const u16*)Bw)[be];
            } else {
                const float* src = (const float*)Bw + be;
                f32x4 v0 = *(const f32x4*)src;
                f32x4 v1 = *(const f32x4*)(src + 4);
                ushort8 tv;
                tv[0]=f2b(v0[0]); tv[1]=f2b(v0[1]); tv[2]=f2b(v0[2]); tv[3]=f2b(v0[3]);
                tv[4]=f2b(v1[0]); tv[5]=f2b(v1[1]); tv[6]=f2b(v1[2]); tv[7]=f2b(v1[3]);
                *(ushort8*)&Bs[r][sc] = tv;
            }
        }
        __syncthreads();
        bf16x8 af[4], bfr[4];
#pragma unroll
        for (int m = 0; m < 4; ++m) af[m]  = *(const bf16x8*)&As[wr + m * 16 + lr][lk];
#pragma unroll
        for (int n = 0; n < 4; ++n) bfr[n] = *(const bf16x8*)&Bs[wc + n * 16 + lr][lk];
#pragma unroll
        for (int m = 0; m < 4; ++m)
#pragma unroll
            for (int n = 0; n < 4; ++n)
                acc[m][n] = __builtin_amdgcn_mfma_f32_16x16x32_bf16(af[m], bfr[n], acc[m][n], 0, 0, 0);
        __syncthreads();
    }

    const int rbase = row0 + wr + (lane >> 4) * 4;
    const int cbase = col0 + wc + lr;
#pragma unroll
    for (int n = 0; n < 4; ++n) {
        int c = cbase + n * 16;
        float bv = (bias != nullptr) ? inload(bias, boff + c, isBf) : 0.0f;
#pragma unroll
        for (int m = 0; m < 4; ++m) {
#pragma unroll
            for (int j = 0; j < 4; ++j) {
                int r = rbase + m * 16 + j;
                float v = acc[m][n][j] + bv;
                if (EPI == 1) v = 0.5f * v * (1.0f + erff(v * 0.70710678118f));
                size_t idx = (size_t)r * N + c;
                if (EPI == 2) {
                    Xres[idx] = Xres[idx] + v;
                } else if (EPI == 3) {
                    if (isBf) ((u16*)Oext)[idx] = f2b(v);
                    else      ((float*)Oext)[idx] = v;
                } else {
                    Obf[idx] = f2b(v);
                }
            }
        }
    }
}

// ---------------- 128x128 2-phase dbuf GEMM, BK=64, optional split-K -------------
template<int EPI>
__global__ __launch_bounds__(256) void gemm2p_k(
    const u16* __restrict__ A, const void* __restrict__ Worig, size_t woff,
    const u16* __restrict__ Wws,
    const void* __restrict__ bias, size_t boff,
    u16* __restrict__ Obf, float* __restrict__ Xres, float* __restrict__ OextA,
    const int* __restrict__ flagp, int N, int Kstride, int Kloop, int nChunk)
{
    const bool isBf = flagp[0] != 0;
    const u16* __restrict__ W = isBf ? ((const u16*)Worig + woff) : Wws;

    __shared__ __align__(16) u16 As[2][128][64];   // 16 KB x2
    __shared__ __align__(16) u16 Bs[2][128][64];   // 64 KB total

    const int totalT = (N >> 7) * 16;
    const int full = totalT * nChunk;
    const int bid = blockIdx.x;
    const int sidall = (bid & 7) * (full >> 3) + (bid >> 3);
    const int chunk = sidall / totalT;
    const int sid = sidall - chunk * totalT;
    const int row0 = (sid & 15) * 128;
    const int col0 = (sid >> 4) * 128;
    const int kbase = chunk * Kloop;

    const int tid  = threadIdx.x;
    const int lane = tid & 63;
    const int wv   = tid >> 6;
    const int wr = (wv >> 1) * 64;
    const int wc = (wv & 1) * 64;
    const int lr = lane & 15;
    const int lk = (lane >> 4) * 8;
    const int srow8 = lane >> 3;
    const int scol8 = (lane & 7) * 8;

    f32x4 acc[4][4] = {};

    auto STAGE = [&](int bb, int k0) {
#pragma unroll
        for (int i = 0; i < 4; ++i) {
            const int r = wv * 32 + i * 8;
            gload16(&A[(size_t)(row0 + r + srow8) * Kstride + kbase + k0 + scol8], &As[bb][r][0]);
            gload16(&W[(size_t)(col0 + r + srow8) * Kstride + kbase + k0 + scol8], &Bs[bb][r][0]);
        }
    };

    STAGE(0, 0);
    __syncthreads();
    int cur = 0;
    for (int k0 = 0; k0 < Kloop; k0 += 64) {
        if (k0 + 64 < Kloop) STAGE(cur ^ 1, k0 + 64);
#pragma unroll
        for (int kk = 0; kk < 2; ++kk) {
            bf16x8 af[4], bfr[4];
#pragma unroll
            for (int m = 0; m < 4; ++m)
                af[m]  = *(const bf16x8*)&As[cur][wr + m * 16 + lr][kk * 32 + lk];
#pragma unroll
            for (int n = 0; n < 4; ++n)
                bfr[n] = *(const bf16x8*)&Bs[cur][wc + n * 16 + lr][kk * 32 + lk];
#pragma unroll
            for (int m = 0; m < 4; ++m)
#pragma unroll
                for (int n = 0; n < 4; ++n)
                    acc[m][n] = __builtin_amdgcn_mfma_f32_16x16x32_bf16(af[m], bfr[n], acc[m][n], 0, 0, 0);
        }
        __syncthreads();
        cur ^= 1;
    }

    const int rbase = row0 + wr + (lane >> 4) * 4;
    const int cbase = col0 + wc + lr;
#pragma unroll
    for (int n = 0; n < 4; ++n) {
        int c = cbase + n * 16;
        float bv = (bias != nullptr && chunk == 0) ? inload(bias, boff + c, isBf) : 0.0f;
#pragma unroll
        for (int m = 0; m < 4; ++m) {
#pragma unroll
            for (int j = 0; j < 4; ++j) {
                int r = rbase + m * 16 + j;
                float v = acc[m][n][j] + bv;
                if (EPI == 1) v = 0.5f * v * (1.0f + erff(v * 0.70710678118f));
                size_t idx = (size_t)r * N + c;
                if (EPI == 2) {
                    Xres[idx] = Xres[idx] + v;
                } else if (EPI == 4) {
                    OextA[(size_t)chunk * NT * N + idx] = v;
                } else {
                    Obf[idx] = f2b(v);
                }
            }
        }
    }
}

// ---------------- 256x256 2-phase dbuf GEMM, BK=64, 128KB LDS (lm_head) ----------
// r7/r10 config: 228us, 112 VGPR. 8-phase port (r12) was SLOWER (258us) -- needs
// T2 swizzle + derived waits to pay (m232); reverted.
template<int EPI>
__global__ __launch_bounds__(512, 2) void gemm3_k(
    const u16* __restrict__ A, const void* __restrict__ Worig, size_t woff,
    const u16* __restrict__ Wws,
    const void* __restrict__ bias, size_t boff,
    u16* __restrict__ Obf, void* __restrict__ Oext,
    const int* __restrict__ flagp, int N, int K)
{
    const bool isBf = flagp[0] != 0;
    const u16* __restrict__ W = isBf ? ((const u16*)Worig + woff) : Wws;

    __shared__ __align__(16) u16 As[2][256][64];   // 32 KB x2
    __shared__ __align__(16) u16 Bs[2][256][64];

    const int total = (N >> 8) * 8;                 // (N/256)*(2048/256)
    const int bid = blockIdx.x;
    const int sid = (bid & 7) * (total >> 3) + (bid >> 3);
    const int row0 = (sid & 7) * 256;
    const int col0 = (sid >> 3) * 256;

    const int tid  = threadIdx.x;
    const int lane = tid & 63;
    const int wv   = tid >> 6;          // 0..7
    const int wm   = wv >> 2;           // 0..1 (128 rows)
    const int wn   = wv & 3;            // 0..3 (64 cols)
    const int lr   = lane & 15;
    const int lk   = (lane >> 4) * 8;
    const int grow = lane >> 3;         // 0..7
    const int gcol = (lane & 7) * 8;

    f32x4 acc[8][4] = {};

    auto STAGE = [&](int bb, int k0) {
#pragma unroll
        for (int j = 0; j < 4; ++j) {
            const int r = j * 64 + wv * 8;
            gload16(&A[(size_t)(row0 + r + grow) * K + k0 + gcol], &As[bb][r][0]);
            gload16(&W[(size_t)(col0 + r + grow) * K + k0 + gcol], &Bs[bb][r][0]);
        }
    };

    STAGE(0, 0);
    __syncthreads();
    int cur = 0;
    for (int k0 = 0; k0 < K; k0 += 64) {
        if (k0 + 64 < K) STAGE(cur ^ 1, k0 + 64);
#pragma unroll
        for (int kk = 0; kk < 2; ++kk) {
            bf16x8 af[8], bfr[4];
#pragma unroll
            for (int m = 0; m < 8; ++m)
                af[m] = *(const bf16x8*)&As[cur][wm * 128 + m * 16 + lr][kk * 32 + lk];
#pragma unroll
            for (int n = 0; n < 4; ++n)
                bfr[n] = *(const bf16x8*)&Bs[cur][wn * 64 + n * 16 + lr][kk * 32 + lk];
#pragma unroll
            for (int m = 0; m < 8; ++m)
#pragma unroll
                for (int n = 0; n < 4; ++n)
                    acc[m][n] = __builtin_amdgcn_mfma_f32_16x16x32_bf16(af[m], bfr[n], acc[m][n], 0, 0, 0);
        }
        __syncthreads();
        cur ^= 1;
    }

    const int rbase = row0 + wm * 128 + (lane >> 4) * 4;
    const int cbase = col0 + wn * 64 + lr;
#pragma unroll
    for (int n = 0; n < 4; ++n) {
        int c = cbase + n * 16;
        float bv = (bias != nullptr) ? inload(bias, boff + c, isBf) : 0.0f;
#pragma unroll
        for (int m = 0; m < 8; ++m) {
#pragma unroll
            for (int j = 0; j < 4; ++j) {
                int r = rbase + m * 16 + j;
                float v = acc[m][n][j] + bv;
                size_t idx = (size_t)r * N + c;
                if (EPI == 3) {
                    if (isBf) ((u16*)Oext)[idx] = f2b(v);
                    else      ((float*)Oext)[idx] = v;
                } else {
                    Obf[idx] = f2b(v);
                }
            }
        }
    }
}

// ---------------- V transpose: vt[(bh*64+d)*Tn + k] = V[b,k,h,d] -----------------
__global__ __launch_bounds__(256) void vtrans_k(
    const u16* __restrict__ qkv, u16* __restrict__ vt)
{
    __shared__ __align__(16) u16 til[64][72];
    const int bid = blockIdx.x;          // bh*16 + kt
    const int kt = bid & 15;
    const int bh = bid >> 4;
    const int b = bh >> 4, hh = bh & 15;
    const int tid = threadIdx.x;
    const int r = tid >> 2;              // 0..63
    const int c = (tid & 3) * 16;        // 0,16,32,48
    const u16* src = qkv + (size_t)(b * Tn + kt * 64 + r) * (3 * Dm) + 2 * Dm + hh * HDm + c;
    *(ushort8*)&til[r][c]     = *(const ushort8*)&src[0];
    *(ushort8*)&til[r][c + 8] = *(const ushort8*)&src[8];
    __syncthreads();
    u16* dst = vt + (size_t)(bh * HDm + r) * Tn + kt * 64 + c;
    ushort8 o1, o2;
#pragma unroll
    for (int j = 0; j < 8; ++j) { o1[j] = til[c + j][r]; o2[j] = til[c + 8 + j][r]; }
    *(ushort8*)&dst[0] = o1;
    *(ushort8*)&dst[8] = o2;
}

// ---------------- MFMA flash attention v2.2 --------------------------------------
// r16's shift-free softmax (exp, deferred denominator) + r17: (a) causal masking
// hoisted out of the main loop -- only the LAST kv-iter can touch the diagonal
// (for it < nkv-1, kv0+31 < q0 <= qrow always); (b) exp2 fold: exp(s/8) =
// exp2(s*0.18033688) -- v_exp_f32 IS exp2, saves one v_mul per element.
__global__ __launch_bounds__(64) void fattn2_k(
    const u16* __restrict__ qkv, const u16* __restrict__ vt, u16* __restrict__ attn)
{
    __shared__ __align__(16) u16 Ps[16][40];

    const int bid = blockIdx.x;
    const int bh  = bid & 31;            // b*16+h
    const int qt  = 63 - (bid >> 5);     // heavy first
    const int b = bh >> 4, hh = bh & 15;
    const int lane = threadIdx.x;
    const int lr = lane & 15;
    const int g  = lane >> 4;            // 0..3
    const int lk = g * 8;

    const size_t qbase = (size_t)b * Tn * 3 * Dm + (size_t)hh * HDm;
    const int q0 = qt * 16;
    const float C = 0.18033688011f;      // 0.125 * log2(e)

    bf16x8 aq[2];
#pragma unroll
    for (int kh = 0; kh < 2; ++kh)
        aq[kh] = *(const bf16x8*)&qkv[qbase + (size_t)(q0 + lr) * (3 * Dm) + kh * 32 + lk];

    f32x4 o[4] = {};
    float lsum[4] = {0.0f, 0.0f, 0.0f, 0.0f};   // per-lane partial denominators

    const u16* kp  = qkv + qbase + Dm;
    const u16* vtp = vt + (size_t)(bh * HDm) * Tn;

    const int nkv = (qt >> 1) + 1;

    // unmasked iterations (kv0+31 < q0 <= qrow)
    for (int it = 0; it < nkv - 1; ++it) {
        const int kv0 = it * 32;

        f32x4 s[2] = {};
#pragma unroll
        for (int n = 0; n < 2; ++n)
#pragma unroll
            for (int kh = 0; kh < 2; ++kh) {
                bf16x8 bk = *(const bf16x8*)&kp[(size_t)(kv0 + n * 16 + lr) * (3 * Dm) + kh * 32 + lk];
                s[n] = __builtin_amdgcn_mfma_f32_16x16x32_bf16(aq[kh], bk, s[n], 0, 0, 0);
            }

#pragma unroll
        for (int j = 0; j < 4; ++j) {
            float p0 = exp2f(s[0][j] * C);
            float p1 = exp2f(s[1][j] * C);
            s[0][j] = p0; s[1][j] = p1;
            lsum[j] += p0 + p1;
        }

#pragma unroll
        for (int n = 0; n < 2; ++n)
#pragma unroll
            for (int j = 0; j < 4; ++j)
                Ps[g * 4 + j][n * 16 + lr] = f2b(s[n][j]);
        bf16x8 ap = *(const bf16x8*)&Ps[lr][lk];

#pragma unroll
        for (int d = 0; d < 4; ++d) {
            bf16x8 bv = *(const bf16x8*)&vtp[(size_t)(d * 16 + lr) * Tn + kv0 + lk];
            o[d] = __builtin_amdgcn_mfma_f32_16x16x32_bf16(ap, bv, o[d], 0, 0, 0);
        }
    }

    // final (masked) iteration
    {
        const int kv0 = (nkv - 1) * 32;

        f32x4 s[2] = {};
#pragma unroll
        for (int n = 0; n < 2; ++n)
#pragma unroll
            for (int kh = 0; kh < 2; ++kh) {
                bf16x8 bk = *(const bf16x8*)&kp[(size_t)(kv0 + n * 16 + lr) * (3 * Dm) + kh * 32 + lk];
                s[n] = __builtin_amdgcn_mfma_f32_16x16x32_bf16(aq[kh], bk, s[n], 0, 0, 0);
            }

#pragma unroll
        for (int j = 0; j < 4; ++j) {
            const int qrow = q0 + g * 4 + j;
            float p0 = (kv0 + lr      <= qrow) ? exp2f(s[0][j] * C) : 0.0f;
            float p1 = (kv0 + 16 + lr <= qrow) ? exp2f(s[1][j] * C) : 0.0f;
            s[0][j] = p0; s[1][j] = p1;
            lsum[j] += p0 + p1;
        }

#pragma unroll
        for (int n = 0; n < 2; ++n)
#pragma unroll
            for (int j = 0; j < 4; ++j)
                Ps[g * 4 + j][n * 16 + lr] = f2b(s[n][j]);
        bf16x8 ap = *(const bf16x8*)&Ps[lr][lk];

#pragma unroll
        for (int d = 0; d < 4; ++d) {
            bf16x8 bv = *(const bf16x8*)&vtp[(size_t)(d * 16 + lr) * Tn + kv0 + lk];
            o[d] = __builtin_amdgcn_mfma_f32_16x16x32_bf16(ap, bv, o[d], 0, 0, 0);
        }
    }

    // one deferred 16-lane reduce per row
    float ltot[4];
#pragma unroll
    for (int j = 0; j < 4; ++j) {
        float rs = lsum[j];
#pragma unroll
        for (int msk = 1; msk < 16; msk <<= 1)
            rs += __shfl_xor(rs, msk);
        ltot[j] = rs;
    }

#pragma unroll
    for (int d = 0; d < 4; ++d)
#pragma unroll
        for (int j = 0; j < 4; ++j) {
            const int qrow = q0 + g * 4 + j;
            attn[(size_t)(b * Tn + qrow) * Dm + hh * HDm + d * 16 + lr] =
                f2b(o[d][j] / ltot[j]);
        }
}

// ---------------- legacy MFMA flash attention (fallback tiers) --------------------
__global__ __launch_bounds__(256) void fattn_k(
    const u16* __restrict__ qkv, u16* __restrict__ attn)
{
    __shared__ __align__(16) u16 Ks[32][72];
    __shared__ __align__(16) u16 Vt[64][40];
    __shared__ __align__(16) u16 Ps[4][16][40];

    const int bid  = blockIdx.x;
    const int pair = bid & 7;
    const int h    = (bid >> 3) & 15;
    const int b    = bid >> 7;
    const int tid  = threadIdx.x;
    const int lane = tid & 63;
    const int wv   = tid >> 6;
    const int lr   = lane & 15;
    const int g    = lane >> 4;
    const int lk   = g * 8;

    const size_t base = (size_t)b * Tn * 3 * Dm + (size_t)h * HDm;
    const int srow = tid >> 3;
    const int sc8  = (tid & 7) * 8;

    for (int half = 0; half < 2; ++half) {
        const int jt = (half == 0) ? pair : 15 - pair;
        const int q0 = jt * 64 + wv * 16;

        bf16x8 aq[2];
#pragma unroll
        for (int kh = 0; kh < 2; ++kh)
            aq[kh] = *(const bf16x8*)&qkv[base + (size_t)(q0 + lr) * (3 * Dm) + kh * 32 + lk];

        f32x4 o[4] = {};
        float mrun[4], lrun[4];
#pragma unroll
        for (int j = 0; j < 4; ++j) { mrun[j] = -3e38f; lrun[j] = 0.0f; }

        const int nkv = 2 * jt + 2;
        for (int it = 0; it < nkv; ++it) {
            const int kv0 = it * 32;
            __syncthreads();
            {
                const size_t rbase = base + (size_t)(kv0 + srow) * (3 * Dm);
                *(ushort8*)&Ks[srow][sc8] = *(const ushort8*)&qkv[rbase + Dm + sc8];
                ushort8 vvv = *(const ushort8*)&qkv[rbase + 2 * Dm + sc8];
#pragma unroll
                for (int jj = 0; jj < 8; ++jj) Vt[sc8 + jj][srow] = vvv[jj];
            }
            __syncthreads();

            f32x4 s[2] = {};
#pragma unroll
            for (int kh = 0; kh < 2; ++kh) {
#pragma unroll
                for (int n = 0; n < 2; ++n) {
                    bf16x8 bk = *(const bf16x8*)&Ks[n * 16 + lr][kh * 32 + lk];
                    s[n] = __builtin_amdgcn_mfma_f32_16x16x32_bf16(aq[kh], bk, s[n], 0, 0, 0);
                }
            }

            float scale[4];
#pragma unroll
            for (int j = 0; j < 4; ++j) {
                const int qrow = q0 + g * 4 + j;
                float v0 = (kv0 + lr      <= qrow) ? s[0][j] * 0.125f : -3e38f;
                float v1 = (kv0 + 16 + lr <= qrow) ? s[1][j] * 0.125f : -3e38f;
                float rm = fmaxf(v0, v1);
#pragma unroll
                for (int msk = 1; msk < 16; msk <<= 1)
                    rm = fmaxf(rm, __shfl_xor(rm, msk));
                float mnew = fmaxf(mrun[j], rm);
                scale[j] = __expf(mrun[j] - mnew);
                float p0 = __expf(v0 - mnew);
                float p1 = __expf(v1 - mnew);
                s[0][j] = p0; s[1][j] = p1;
                float rs = p0 + p1;
#pragma unroll
                for (int msk = 1; msk < 16; msk <<= 1)
                    rs += __shfl_xor(rs, msk);
                lrun[j] = lrun[j] * scale[j] + rs;
                mrun[j] = mnew;
            }

#pragma unroll
            for (int n = 0; n < 2; ++n)
#pragma unroll
                for (int j = 0; j < 4; ++j)
                    Ps[wv][g * 4 + j][n * 16 + lr] = f2b(s[n][j]);
            bf16x8 ap = *(const bf16x8*)&Ps[wv][lr][lk];

#pragma unroll
            for (int d = 0; d < 4; ++d) {
                f32x4 c = o[d];
#pragma unroll
                for (int j = 0; j < 4; ++j) c[j] *= scale[j];
                bf16x8 bv = *(const bf16x8*)&Vt[d * 16 + lr][lk];
                o[d] = __builtin_amdgcn_mfma_f32_16x16x32_bf16(ap, bv, c, 0, 0, 0);
            }
        }

#pragma unroll
        for (int d = 0; d < 4; ++d) {
#pragma unroll
            for (int j = 0; j < 4; ++j) {
                const int qrow = q0 + g * 4 + j;
                attn[(size_t)(b * Tn + qrow) * Dm + h * HDm + d * 16 + lr] =
                    f2b(o[d][j] / lrun[j]);
            }
        }
    }
}

// ---------------- host orchestration ---------------------------------------------
extern "C" void kernel_launch(void* const* d_in, const int* in_sizes, int n_in,
                              void* d_out, int out_size, void* d_ws, size_t ws_size,
                              hipStream_t stream)
{
    const int*  ids       = (const int*)d_in[0];
    const void* text_emb  = d_in[1];
    const void* pos_emb   = d_in[2];
    const void* qkv_w     = d_in[3];
    const void* qkv_b     = d_in[4];
    const void* out_w     = d_in[5];
    const void* out_b     = d_in[6];
    const void* ln1_w     = d_in[7];
    const void* ln1_b     = d_in[8];
    const void* ln2_w     = d_in[9];
    const void* ln2_b     = d_in[10];
    const void* w1        = d_in[11];
    const void* b1        = d_in[12];
    const void* w2        = d_in[13];
    const void* b2        = d_in[14];
    const void* lnf_w     = d_in[15];
    const void* lnf_b     = d_in[16];
    const void* lm_head_w = d_in[17];

    char* ws = (char*)d_ws;
    size_t used = 0;
    auto carve = [&](size_t bytes) { char* p = ws + used; used += (bytes + 15) & ~15ull; return p; };

    int*   flag = (int*)  carve(16);
    float* x    = (float*)carve((size_t)NT * Dm * 4);
    u16*   h    = (u16*)  carve((size_t)NT * Dm * 2);       // aliased by vt
    u16*   qkv  = (u16*)  carve((size_t)NT * 3 * Dm * 2);   // aliased by Pf[0..1]
    u16*   attn = (u16*)  carve((size_t)NT * Dm * 2);
    u16*   u    = (u16*)  carve((size_t)NT * DFF * 2);      // aliased by Pa[0..1]

    u16*   vt = h;
    float* Pf = (float*)qkv;
    float* Pa = (float*)u;

    const size_t nLM  = (size_t)Vn * Dm;
    const size_t nQKV = (size_t)Ln * 3 * Dm * Dm;
    const size_t nOUT = (size_t)Ln * Dm * Dm;
    const size_t nW1  = (size_t)Ln * DFF * Dm;
    const size_t nW2  = (size_t)Ln * Dm * DFF;

    u16* wsLM  = (u16*)carve(nLM * 2);
    size_t lm_used = used;
    u16* wsQKV = (u16*)carve(nQKV * 2);
    u16* wsOUT = (u16*)carve(nOUT * 2);
    u16* wsW1  = (u16*)carve(nW1 * 2);
    u16* wsW2  = (u16*)carve(nW2 * 2);
    size_t t2_used = used;

    const int tier = (ws_size >= t2_used) ? 2 : (ws_size >= lm_used ? 1 : 0);

    dim3 blk(256);

    sniff_k<<<1, blk, 0, stream>>>(text_emb, flag);

    if (tier >= 2) {
        // one merged launch: LM 16000 | QKV 12288 | OUT 4096 | W1 16384 | W2 16384
        conv5_k<<<65152, blk, 0, stream>>>(
            lm_head_w, wsLM, qkv_w, wsQKV, out_w, wsOUT, w1, wsW1, w2, wsW2, flag);
    } else if (tier == 1) {
        conv_k<<<nLM / 2048, blk, 0, stream>>>(lm_head_w, wsLM, flag);
    }

    embed_k<<<NT, blk, 0, stream>>>(ids, text_emb, pos_emb, x, flag);

    if (tier >= 2) {
        for (int l = 0; l < Ln; ++l) {
            size_t oQW = (size_t)l * 3 * Dm * Dm, oQB = (size_t)l * 3 * Dm;
            size_t oOW = (size_t)l * Dm * Dm,     oOB = (size_t)l * Dm;
            size_t oW1 = (size_t)l * DFF * Dm,    oB1 = (size_t)l * DFF;
            size_t oW2 = (size_t)l * Dm * DFF,    oB2 = (size_t)l * Dm;
            size_t oLN = (size_t)l * Dm;

            lnfuse_k<<<NT, blk, 0, stream>>>(x, Pf, (l == 0) ? 0 : 2,
                                             ln1_w, ln1_b, oLN, h, flag);
            gemm2p_k<0><<<16 * (3 * Dm / 128), blk, 0, stream>>>(
                h, qkv_w, oQW, wsQKV + oQW, qkv_b, oQB, qkv, nullptr, nullptr,
                flag, 3 * Dm, Dm, Dm, 1);
            vtrans_k<<<32 * 16, blk, 0, stream>>>(qkv, vt);
            fattn2_k<<<2048, dim3(64), 0, stream>>>(qkv, vt, attn);
            gemm2p_k<4><<<2 * 16 * (Dm / 128), blk, 0, stream>>>(
                attn, out_w, oOW, wsOUT + oOW, out_b, oOB, nullptr, nullptr, Pa,
                flag, Dm, Dm, Dm / 2, 2);
            lnfuse_k<<<NT, blk, 0, stream>>>(x, Pa, 2, ln2_w, ln2_b, oLN, h, flag);
            gemm2p_k<1><<<16 * (DFF / 128), blk, 0, stream>>>(
                h, w1, oW1, wsW1 + oW1, b1, oB1, u, nullptr, nullptr,
                flag, DFF, Dm, Dm, 1);
            gemm2p_k<4><<<2 * 16 * (Dm / 128), blk, 0, stream>>>(
                u, w2, oW2, wsW2 + oW2, b2, oB2, nullptr, nullptr, Pf,
                flag, Dm, DFF, DFF / 2, 2);
        }
        lnfuse_k<<<NT, blk, 0, stream>>>(x, Pf, 2, lnf_w, lnf_b, 0, h, flag);
        gemm3_k<3><<<8 * (Vn / 256), dim3(512), 0, stream>>>(
            h, lm_head_w, 0, wsLM, nullptr, 0, nullptr, d_out, flag, Vn, Dm);
    } else {
        for (int l = 0; l < Ln; ++l) {
            size_t oQW = (size_t)l * 3 * Dm * Dm, oQB = (size_t)l * 3 * Dm;
            size_t oOW = (size_t)l * Dm * Dm,     oOB = (size_t)l * Dm;
            size_t oW1 = (size_t)l * DFF * Dm,    oB1 = (size_t)l * DFF;
            size_t oW2 = (size_t)l * Dm * DFF,    oB2 = (size_t)l * Dm;
            size_t oLN = (size_t)l * Dm;

            ln_k<<<NT, blk, 0, stream>>>(x, ln1_w, ln1_b, oLN, h, flag);
            gemm_k<0><<<dim3(3 * Dm / 128, NT / 128), blk, 0, stream>>>(
                h, qkv_w, oQW, qkv_b, oQB, qkv, nullptr, nullptr, flag, NT, 3 * Dm, Dm);
            fattn_k<<<2 * Hn * 8, blk, 0, stream>>>(qkv, attn);
            gemm_k<2><<<dim3(Dm / 128, NT / 128), blk, 0, stream>>>(
                attn, out_w, oOW, out_b, oOB, nullptr, x, nullptr, flag, NT, Dm, Dm);
            ln_k<<<NT, blk, 0, stream>>>(x, ln2_w, ln2_b, oLN, h, flag);
            gemm_k<1><<<dim3(DFF / 128, NT / 128), blk, 0, stream>>>(
                h, w1, oW1, b1, oB1, u, nullptr, nullptr, flag, NT, DFF, Dm);
            gemm_k<2><<<dim3(Dm / 128, NT / 128), blk, 0, stream>>>(
                u, w2, oW2, b2, oB2, nullptr, x, nullptr, flag, NT, Dm, DFF);
        }
        ln_k<<<NT, blk, 0, stream>>>(x, lnf_w, lnf_b, 0, h, flag);
        if (tier == 1)
            gemm3_k<3><<<8 * (Vn / 256), dim3(512), 0, stream>>>(
                h, lm_head_w, 0, wsLM, nullptr, 0, nullptr, d_out, flag, Vn, Dm);
        else
            gemm_k<3><<<dim3(Vn / 128, NT / 128), blk, 0, stream>>>(
                h, lm_head_w, 0, nullptr, 0, nullptr, nullptr, d_out, flag, NT, Vn, Dm);
    }
}

// Round 18
// 2065.196 us; speedup vs baseline: 1.0138x; 1.0138x over previous
//
#include <hip/hip_runtime.h>
#include <hip/hip_bf16.h>

// Problem constants
#define Hn 16
#define Dm 1024
#define HDm 64
#define Tn 1024
#define NT 2048      // B*T
#define Ln 8
#define Vn 32000
#define DFF 4096

typedef unsigned short u16;
typedef unsigned short ushort8 __attribute__((ext_vector_type(8)));
typedef __bf16 bf16x8 __attribute__((ext_vector_type(8)));
typedef float f32x4 __attribute__((ext_vector_type(4)));

__device__ __forceinline__ float b2f(u16 u) {
    union { unsigned int i; float f; } x; x.i = ((unsigned int)u) << 16; return x.f;
}
__device__ __forceinline__ u16 f2b(float f) {
    union { float f; unsigned int i; } x; x.f = f;
    unsigned int r = x.i + 0x7FFFu + ((x.i >> 16) & 1u);
    return (u16)(r >> 16);
}
__device__ __forceinline__ float inload(const void* p, size_t idx, bool isBf) {
    return isBf ? b2f(((const u16*)p)[idx]) : ((const float*)p)[idx];
}

// global -> LDS direct copy, 16B per lane. LDS dest must be the wave-uniform base;
// HW adds lane*16. Low 32 bits of a generic LDS address = DS offset (verified r4).
__device__ __forceinline__ void gload16(const void* g, void* l) {
    const unsigned int __attribute__((address_space(1)))* gp =
        (const unsigned int __attribute__((address_space(1)))*)(unsigned long long)g;
    unsigned int __attribute__((address_space(3)))* lp =
        (unsigned int __attribute__((address_space(3)))*)(unsigned int)(unsigned long long)l;
    __builtin_amdgcn_global_load_lds(gp, lp, 16, 0, 0);
}

// ---------------- dtype sniffer ---------------------------------------------------
__global__ __launch_bounds__(256) void sniff_k(const void* temb, int* flag)
{
    int tid = threadIdx.x;
    const u16* p = (const u16*)temb;
    int cnt = 0;
    for (int i = tid; i < 4096; i += 256) {
        float v = b2f(p[2 * i]);
        if (!(fabsf(v) < 8.0f)) cnt++;
    }
    __shared__ int red[256];
    red[tid] = cnt;
    __syncthreads();
    for (int st = 128; st > 0; st >>= 1) {
        if (tid < st) red[tid] += red[tid + st];
        __syncthreads();
    }
    if (tid == 0) flag[0] = (red[0] < 8) ? 1 : 0;   // 1 = bf16, 0 = f32
}

// ---------------- weight f32 -> bf16 preconversion (no-op if already bf16) -------
__global__ __launch_bounds__(256) void conv_k(
    const void* __restrict__ src, u16* __restrict__ dst, const int* __restrict__ flagp)
{
    if (flagp[0] != 0) return;
    size_t i = ((size_t)blockIdx.x * 256 + threadIdx.x) * 8;
    const float* s = (const float*)src + i;
    f32x4 a = *(const f32x4*)s;
    f32x4 b = *(const f32x4*)(s + 4);
    ushort8 o;
    o[0]=f2b(a[0]); o[1]=f2b(a[1]); o[2]=f2b(a[2]); o[3]=f2b(a[3]);
    o[4]=f2b(b[0]); o[5]=f2b(b[1]); o[6]=f2b(b[2]); o[7]=f2b(b[3]);
    *(ushort8*)(dst + i) = o;
}

// ---------------- embed ----------------------------------------------------------
__global__ __launch_bounds__(256) void embed_k(
    const int* __restrict__ ids, const void* __restrict__ temb,
    const void* __restrict__ pemb, float* __restrict__ x,
    const int* __restrict__ flagp)
{
    const bool isBf = flagp[0] != 0;
    int n = blockIdx.x;
    int t = n & (Tn - 1);
    int id = ids[n];
    int d = threadIdx.x * 4;
    float* xo = x + (size_t)n * Dm + d;
#pragma unroll
    for (int j = 0; j < 4; ++j)
        xo[j] = inload(temb, (size_t)id * Dm + d + j, isBf)
              + inload(pemb, (size_t)t  * Dm + d + j, isBf);
}

// ---------------- legacy layernorm (fallback tiers) ------------------------------
__global__ __launch_bounds__(256) void ln_k(
    const float* __restrict__ x, const void* __restrict__ g,
    const void* __restrict__ bta, size_t goff, u16* __restrict__ hout,
    const int* __restrict__ flagp)
{
    const bool isBf = flagp[0] != 0;
    int n = blockIdx.x;
    int tid = threadIdx.x;
    const float* xr = x + (size_t)n * Dm;
    f32x4 v = *(const f32x4*)&xr[tid * 4];
    float s = v[0] + v[1] + v[2] + v[3];
    float ss = v[0]*v[0] + v[1]*v[1] + v[2]*v[2] + v[3]*v[3];
    __shared__ float r1[256], r2[256];
    r1[tid] = s; r2[tid] = ss;
    __syncthreads();
    for (int st = 128; st > 0; st >>= 1) {
        if (tid < st) { r1[tid] += r1[tid + st]; r2[tid] += r2[tid + st]; }
        __syncthreads();
    }
    float mean = r1[0] * (1.0f / Dm);
    float var  = r2[0] * (1.0f / Dm) - mean * mean;
    float rs = rsqrtf(var + 1e-5f);
    u16* ho = hout + (size_t)n * Dm + tid * 4;
#pragma unroll
    for (int j = 0; j < 4; ++j) {
        float gv = inload(g,   goff + tid * 4 + j, isBf);
        float bv = inload(bta, goff + tid * 4 + j, isBf);
        ho[j] = f2b((v[j] - mean) * rs * gv + bv);
    }
}

// ---------------- fused: x += P0+P1; h = LN(x)*g+b  (nP = 0 or 2) ----------------
__global__ __launch_bounds__(256) void lnfuse_k(
    float* __restrict__ x, const float* __restrict__ P, int nP,
    const void* __restrict__ g, const void* __restrict__ bta, size_t goff,
    u16* __restrict__ hout, const int* __restrict__ flagp)
{
    const bool isBf = flagp[0] != 0;
    int n = blockIdx.x;
    int tid = threadIdx.x;
    float* xr = x + (size_t)n * Dm;
    f32x4 v = *(const f32x4*)&xr[tid * 4];
    if (nP == 2) {
        const float* p0 = P + (size_t)n * Dm;
        const float* p1 = P + (size_t)NT * Dm + (size_t)n * Dm;
        f32x4 a = *(const f32x4*)&p0[tid * 4];
        f32x4 b = *(const f32x4*)&p1[tid * 4];
#pragma unroll
        for (int j = 0; j < 4; ++j) v[j] = v[j] + a[j] + b[j];
        *(f32x4*)&xr[tid * 4] = v;          // write back residual stream
    }
    float s = v[0] + v[1] + v[2] + v[3];
    float ss = v[0]*v[0] + v[1]*v[1] + v[2]*v[2] + v[3]*v[3];
    __shared__ float r1[256], r2[256];
    r1[tid] = s; r2[tid] = ss;
    __syncthreads();
    for (int st = 128; st > 0; st >>= 1) {
        if (tid < st) { r1[tid] += r1[tid + st]; r2[tid] += r2[tid + st]; }
        __syncthreads();
    }
    float mean = r1[0] * (1.0f / Dm);
    float var  = r2[0] * (1.0f / Dm) - mean * mean;
    float rs = rsqrtf(var + 1e-5f);
    u16* ho = hout + (size_t)n * Dm + tid * 4;
#pragma unroll
    for (int j = 0; j < 4; ++j) {
        float gv = inload(g,   goff + tid * 4 + j, isBf);
        float bv = inload(bta, goff + tid * 4 + j, isBf);
        ho[j] = f2b((v[j] - mean) * rs * gv + bv);
    }
}

// ---------------- legacy dual-dtype MFMA GEMM (fallback path) --------------------
template<int EPI>
__global__ __launch_bounds__(256) void gemm_k(
    const u16* __restrict__ A, const void* __restrict__ Bw, size_t woff,
    const void* __restrict__ bias, size_t boff,
    u16* __restrict__ Obf, float* __restrict__ Xres, void* __restrict__ Oext,
    const int* __restrict__ flagp, int M, int N, int K)
{
    const bool isBf = flagp[0] != 0;
    __shared__ __align__(16) u16 As[128][40];
    __shared__ __align__(16) u16 Bs[128][40];
    const int tid  = threadIdx.x;
    const int lane = tid & 63;
    const int wave = tid >> 6;
    const int wr = (wave >> 1) * 64;
    const int wc = (wave & 1) * 64;
    const int row0 = blockIdx.y * 128;
    const int col0 = blockIdx.x * 128;
    const int lr = lane & 15;
    const int lk = (lane >> 4) * 8;
    const int sr = tid >> 2;
    const int sc = (tid & 3) * 8;

    f32x4 acc[4][4] = {};

    for (int k0 = 0; k0 < K; k0 += 32) {
#pragma unroll
        for (int i = 0; i < 2; ++i) {
            int r = sr + i * 64;
            *(ushort8*)&As[r][sc] = *(const ushort8*)&A[(size_t)(row0 + r) * K + k0 + sc];
            size_t be = woff + (size_t)(col0 + r) * K + k0 + sc;
            if (isBf) {
                *(ushort8*)&Bs[r][sc] = *(const ushort8*)&((const u16*)Bw)[be];
            } else {
                const float* src = (const float*)Bw + be;
                f32x4 v0 = *(const f32x4*)src;
                f32x4 v1 = *(const f32x4*)(src + 4);
                ushort8 tv;
                tv[0]=f2b(v0[0]); tv[1]=f2b(v0[1]); tv[2]=f2b(v0[2]); tv[3]=f2b(v0[3]);
                tv[4]=f2b(v1[0]); tv[5]=f2b(v1[1]); tv[6]=f2b(v1[2]); tv[7]=f2b(v1[3]);
                *(ushort8*)&Bs[r][sc] = tv;
            }
        }
        __syncthreads();
        bf16x8 af[4], bfr[4];
#pragma unroll
        for (int m = 0; m < 4; ++m) af[m]  = *(const bf16x8*)&As[wr + m * 16 + lr][lk];
#pragma unroll
        for (int n = 0; n < 4; ++n) bfr[n] = *(const bf16x8*)&Bs[wc + n * 16 + lr][lk];
#pragma unroll
        for (int m = 0; m < 4; ++m)
#pragma unroll
            for (int n = 0; n < 4; ++n)
                acc[m][n] = __builtin_amdgcn_mfma_f32_16x16x32_bf16(af[m], bfr[n], acc[m][n], 0, 0, 0);
        __syncthreads();
    }

    const int rbase = row0 + wr + (lane >> 4) * 4;
    const int cbase = col0 + wc + lr;
#pragma unroll
    for (int n = 0; n < 4; ++n) {
        int c = cbase + n * 16;
        float bv = (bias != nullptr) ? inload(bias, boff + c, isBf) : 0.0f;
#pragma unroll
        for (int m = 0; m < 4; ++m) {
#pragma unroll
            for (int j = 0; j < 4; ++j) {
                int r = rbase + m * 16 + j;
                float v = acc[m][n][j] + bv;
                if (EPI == 1) v = 0.5f * v * (1.0f + erff(v * 0.70710678118f));
                size_t idx = (size_t)r * N + c;
                if (EPI == 2) {
                    Xres[idx] = Xres[idx] + v;
                } else if (EPI == 3) {
                    if (isBf) ((u16*)Oext)[idx] = f2b(v);
                    else      ((float*)Oext)[idx] = v;
                } else {
                    Obf[idx] = f2b(v);
                }
            }
        }
    }
}

// ---------------- 128x128 2-phase dbuf GEMM, BK=64, optional split-K -------------
template<int EPI>
__global__ __launch_bounds__(256) void gemm2p_k(
    const u16* __restrict__ A, const void* __restrict__ Worig, size_t woff,
    const u16* __restrict__ Wws,
    const void* __restrict__ bias, size_t boff,
    u16* __restrict__ Obf, float* __restrict__ Xres, float* __restrict__ OextA,
    const int* __restrict__ flagp, int N, int Kstride, int Kloop, int nChunk)
{
    const bool isBf = flagp[0] != 0;
    const u16* __restrict__ W = isBf ? ((const u16*)Worig + woff) : Wws;

    __shared__ __align__(16) u16 As[2][128][64];   // 16 KB x2
    __shared__ __align__(16) u16 Bs[2][128][64];   // 64 KB total

    const int totalT = (N >> 7) * 16;
    const int full = totalT * nChunk;
    const int bid = blockIdx.x;
    const int sidall = (bid & 7) * (full >> 3) + (bid >> 3);
    const int chunk = sidall / totalT;
    const int sid = sidall - chunk * totalT;
    const int row0 = (sid & 15) * 128;
    const int col0 = (sid >> 4) * 128;
    const int kbase = chunk * Kloop;

    const int tid  = threadIdx.x;
    const int lane = tid & 63;
    const int wv   = tid >> 6;
    const int wr = (wv >> 1) * 64;
    const int wc = (wv & 1) * 64;
    const int lr = lane & 15;
    const int lk = (lane >> 4) * 8;
    const int srow8 = lane >> 3;
    const int scol8 = (lane & 7) * 8;

    f32x4 acc[4][4] = {};

    auto STAGE = [&](int bb, int k0) {
#pragma unroll
        for (int i = 0; i < 4; ++i) {
            const int r = wv * 32 + i * 8;
            gload16(&A[(size_t)(row0 + r + srow8) * Kstride + kbase + k0 + scol8], &As[bb][r][0]);
            gload16(&W[(size_t)(col0 + r + srow8) * Kstride + kbase + k0 + scol8], &Bs[bb][r][0]);
        }
    };

    STAGE(0, 0);
    __syncthreads();
    int cur = 0;
    for (int k0 = 0; k0 < Kloop; k0 += 64) {
        if (k0 + 64 < Kloop) STAGE(cur ^ 1, k0 + 64);
#pragma unroll
        for (int kk = 0; kk < 2; ++kk) {
            bf16x8 af[4], bfr[4];
#pragma unroll
            for (int m = 0; m < 4; ++m)
                af[m]  = *(const bf16x8*)&As[cur][wr + m * 16 + lr][kk * 32 + lk];
#pragma unroll
            for (int n = 0; n < 4; ++n)
                bfr[n] = *(const bf16x8*)&Bs[cur][wc + n * 16 + lr][kk * 32 + lk];
#pragma unroll
            for (int m = 0; m < 4; ++m)
#pragma unroll
                for (int n = 0; n < 4; ++n)
                    acc[m][n] = __builtin_amdgcn_mfma_f32_16x16x32_bf16(af[m], bfr[n], acc[m][n], 0, 0, 0);
        }
        __syncthreads();
        cur ^= 1;
    }

    const int rbase = row0 + wr + (lane >> 4) * 4;
    const int cbase = col0 + wc + lr;
#pragma unroll
    for (int n = 0; n < 4; ++n) {
        int c = cbase + n * 16;
        float bv = (bias != nullptr && chunk == 0) ? inload(bias, boff + c, isBf) : 0.0f;
#pragma unroll
        for (int m = 0; m < 4; ++m) {
#pragma unroll
            for (int j = 0; j < 4; ++j) {
                int r = rbase + m * 16 + j;
                float v = acc[m][n][j] + bv;
                if (EPI == 1) v = 0.5f * v * (1.0f + erff(v * 0.70710678118f));
                size_t idx = (size_t)r * N + c;
                if (EPI == 2) {
                    Xres[idx] = Xres[idx] + v;
                } else if (EPI == 4) {
                    OextA[(size_t)chunk * NT * N + idx] = v;
                } else {
                    Obf[idx] = f2b(v);
                }
            }
        }
    }
}

// ---------------- 256x256 2-phase dbuf GEMM, BK=64, 128KB LDS (lm_head) ----------
// r7/r10 config: 228us, 112 VGPR. 8-phase port (r12) was SLOWER (258us) -- needs
// T2 swizzle + derived waits to pay (m232); reverted.
template<int EPI>
__global__ __launch_bounds__(512, 2) void gemm3_k(
    const u16* __restrict__ A, const void* __restrict__ Worig, size_t woff,
    const u16* __restrict__ Wws,
    const void* __restrict__ bias, size_t boff,
    u16* __restrict__ Obf, void* __restrict__ Oext,
    const int* __restrict__ flagp, int N, int K)
{
    const bool isBf = flagp[0] != 0;
    const u16* __restrict__ W = isBf ? ((const u16*)Worig + woff) : Wws;

    __shared__ __align__(16) u16 As[2][256][64];   // 32 KB x2
    __shared__ __align__(16) u16 Bs[2][256][64];

    const int total = (N >> 8) * 8;                 // (N/256)*(2048/256)
    const int bid = blockIdx.x;
    const int sid = (bid & 7) * (total >> 3) + (bid >> 3);
    const int row0 = (sid & 7) * 256;
    const int col0 = (sid >> 3) * 256;

    const int tid  = threadIdx.x;
    const int lane = tid & 63;
    const int wv   = tid >> 6;          // 0..7
    const int wm   = wv >> 2;           // 0..1 (128 rows)
    const int wn   = wv & 3;            // 0..3 (64 cols)
    const int lr   = lane & 15;
    const int lk   = (lane >> 4) * 8;
    const int grow = lane >> 3;         // 0..7
    const int gcol = (lane & 7) * 8;

    f32x4 acc[8][4] = {};

    auto STAGE = [&](int bb, int k0) {
#pragma unroll
        for (int j = 0; j < 4; ++j) {
            const int r = j * 64 + wv * 8;
            gload16(&A[(size_t)(row0 + r + grow) * K + k0 + gcol], &As[bb][r][0]);
            gload16(&W[(size_t)(col0 + r + grow) * K + k0 + gcol], &Bs[bb][r][0]);
        }
    };

    STAGE(0, 0);
    __syncthreads();
    int cur = 0;
    for (int k0 = 0; k0 < K; k0 += 64) {
        if (k0 + 64 < K) STAGE(cur ^ 1, k0 + 64);
#pragma unroll
        for (int kk = 0; kk < 2; ++kk) {
            bf16x8 af[8], bfr[4];
#pragma unroll
            for (int m = 0; m < 8; ++m)
                af[m] = *(const bf16x8*)&As[cur][wm * 128 + m * 16 + lr][kk * 32 + lk];
#pragma unroll
            for (int n = 0; n < 4; ++n)
                bfr[n] = *(const bf16x8*)&Bs[cur][wn * 64 + n * 16 + lr][kk * 32 + lk];
#pragma unroll
            for (int m = 0; m < 8; ++m)
#pragma unroll
                for (int n = 0; n < 4; ++n)
                    acc[m][n] = __builtin_amdgcn_mfma_f32_16x16x32_bf16(af[m], bfr[n], acc[m][n], 0, 0, 0);
        }
        __syncthreads();
        cur ^= 1;
    }

    const int rbase = row0 + wm * 128 + (lane >> 4) * 4;
    const int cbase = col0 + wn * 64 + lr;
#pragma unroll
    for (int n = 0; n < 4; ++n) {
        int c = cbase + n * 16;
        float bv = (bias != nullptr) ? inload(bias, boff + c, isBf) : 0.0f;
#pragma unroll
        for (int m = 0; m < 8; ++m) {
#pragma unroll
            for (int j = 0; j < 4; ++j) {
                int r = rbase + m * 16 + j;
                float v = acc[m][n][j] + bv;
                size_t idx = (size_t)r * N + c;
                if (EPI == 3) {
                    if (isBf) ((u16*)Oext)[idx] = f2b(v);
                    else      ((float*)Oext)[idx] = v;
                } else {
                    Obf[idx] = f2b(v);
                }
            }
        }
    }
}

// ---------------- V transpose: vt[(bh*64+d)*Tn + k] = V[b,k,h,d] -----------------
__global__ __launch_bounds__(256) void vtrans_k(
    const u16* __restrict__ qkv, u16* __restrict__ vt)
{
    __shared__ __align__(16) u16 til[64][72];
    const int bid = blockIdx.x;          // bh*16 + kt
    const int kt = bid & 15;
    const int bh = bid >> 4;
    const int b = bh >> 4, hh = bh & 15;
    const int tid = threadIdx.x;
    const int r = tid >> 2;              // 0..63
    const int c = (tid & 3) * 16;        // 0,16,32,48
    const u16* src = qkv + (size_t)(b * Tn + kt * 64 + r) * (3 * Dm) + 2 * Dm + hh * HDm + c;
    *(ushort8*)&til[r][c]     = *(const ushort8*)&src[0];
    *(ushort8*)&til[r][c + 8] = *(const ushort8*)&src[8];
    __syncthreads();
    u16* dst = vt + (size_t)(bh * HDm + r) * Tn + kt * 64 + c;
    ushort8 o1, o2;
#pragma unroll
    for (int j = 0; j < 8; ++j) { o1[j] = til[c + j][r]; o2[j] = til[c + 8 + j][r]; }
    *(ushort8*)&dst[0] = o1;
    *(ushort8*)&dst[8] = o2;
}

// ---------------- MFMA flash attention v2.1: shift-free softmax ------------------
// Softmax is shift-invariant; scores are LN-bounded (sigma~3, overflow needs s>78
// = ~25 sigma) so the online max is unnecessary: p = exp(s/8) directly, and the
// 16-lane sum-reduce is DEFERRED to after the kv loop (per-lane partials). This
// deletes ALL shuffles, the fmax chain, the scale exp and the 16 O-rescale mults
// from the inner loop. (r17's mask-hoist + exp2 fold were neutral-to-negative --
// reverted to this r16 form, the verified best at 2073us.)
__global__ __launch_bounds__(64) void fattn2_k(
    const u16* __restrict__ qkv, const u16* __restrict__ vt, u16* __restrict__ attn)
{
    __shared__ __align__(16) u16 Ps[16][40];

    const int bid = blockIdx.x;
    const int bh  = bid & 31;            // b*16+h
    const int qt  = 63 - (bid >> 5);     // heavy first
    const int b = bh >> 4, hh = bh & 15;
    const int lane = threadIdx.x;
    const int lr = lane & 15;
    const int g  = lane >> 4;            // 0..3
    const int lk = g * 8;

    const size_t qbase = (size_t)b * Tn * 3 * Dm + (size_t)hh * HDm;
    const int q0 = qt * 16;

    bf16x8 aq[2];
#pragma unroll
    for (int kh = 0; kh < 2; ++kh)
        aq[kh] = *(const bf16x8*)&qkv[qbase + (size_t)(q0 + lr) * (3 * Dm) + kh * 32 + lk];

    f32x4 o[4] = {};
    float lsum[4] = {0.0f, 0.0f, 0.0f, 0.0f};   // per-lane partial denominators

    const u16* kp  = qkv + qbase + Dm;
    const u16* vtp = vt + (size_t)(bh * HDm) * Tn;

    const int nkv = (qt >> 1) + 1;
    for (int it = 0; it < nkv; ++it) {
        const int kv0 = it * 32;

        f32x4 s[2] = {};
#pragma unroll
        for (int n = 0; n < 2; ++n)
#pragma unroll
            for (int kh = 0; kh < 2; ++kh) {
                bf16x8 bk = *(const bf16x8*)&kp[(size_t)(kv0 + n * 16 + lr) * (3 * Dm) + kh * 32 + lk];
                s[n] = __builtin_amdgcn_mfma_f32_16x16x32_bf16(aq[kh], bk, s[n], 0, 0, 0);
            }

        // p = exp(s/8), causal-masked; accumulate per-lane denominator partials
#pragma unroll
        for (int j = 0; j < 4; ++j) {
            const int qrow = q0 + g * 4 + j;
            float p0 = (kv0 + lr      <= qrow) ? __expf(s[0][j] * 0.125f) : 0.0f;
            float p1 = (kv0 + 16 + lr <= qrow) ? __expf(s[1][j] * 0.125f) : 0.0f;
            s[0][j] = p0; s[1][j] = p1;
            lsum[j] += p0 + p1;
        }

        // P (C-layout) -> LDS -> A-fragment layout (per-wave, waitcnt only)
#pragma unroll
        for (int n = 0; n < 2; ++n)
#pragma unroll
            for (int j = 0; j < 4; ++j)
                Ps[g * 4 + j][n * 16 + lr] = f2b(s[n][j]);
        bf16x8 ap = *(const bf16x8*)&Ps[lr][lk];

        // O += P @ V (no rescale needed -- fixed shift)
#pragma unroll
        for (int d = 0; d < 4; ++d) {
            bf16x8 bv = *(const bf16x8*)&vtp[(size_t)(d * 16 + lr) * Tn + kv0 + lk];
            o[d] = __builtin_amdgcn_mfma_f32_16x16x32_bf16(ap, bv, o[d], 0, 0, 0);
        }
    }

    // one deferred 16-lane reduce per row
    float ltot[4];
#pragma unroll
    for (int j = 0; j < 4; ++j) {
        float rs = lsum[j];
#pragma unroll
        for (int msk = 1; msk < 16; msk <<= 1)
            rs += __shfl_xor(rs, msk);
        ltot[j] = rs;
    }

#pragma unroll
    for (int d = 0; d < 4; ++d)
#pragma unroll
        for (int j = 0; j < 4; ++j) {
            const int qrow = q0 + g * 4 + j;
            attn[(size_t)(b * Tn + qrow) * Dm + hh * HDm + d * 16 + lr] =
                f2b(o[d][j] / ltot[j]);
        }
}

// ---------------- legacy MFMA flash attention (fallback tiers) --------------------
__global__ __launch_bounds__(256) void fattn_k(
    const u16* __restrict__ qkv, u16* __restrict__ attn)
{
    __shared__ __align__(16) u16 Ks[32][72];
    __shared__ __align__(16) u16 Vt[64][40];
    __shared__ __align__(16) u16 Ps[4][16][40];

    const int bid  = blockIdx.x;
    const int pair = bid & 7;
    const int h    = (bid >> 3) & 15;
    const int b    = bid >> 7;
    const int tid  = threadIdx.x;
    const int lane = tid & 63;
    const int wv   = tid >> 6;
    const int lr   = lane & 15;
    const int g    = lane >> 4;
    const int lk   = g * 8;

    const size_t base = (size_t)b * Tn * 3 * Dm + (size_t)h * HDm;
    const int srow = tid >> 3;
    const int sc8  = (tid & 7) * 8;

    for (int half = 0; half < 2; ++half) {
        const int jt = (half == 0) ? pair : 15 - pair;
        const int q0 = jt * 64 + wv * 16;

        bf16x8 aq[2];
#pragma unroll
        for (int kh = 0; kh < 2; ++kh)
            aq[kh] = *(const bf16x8*)&qkv[base + (size_t)(q0 + lr) * (3 * Dm) + kh * 32 + lk];

        f32x4 o[4] = {};
        float mrun[4], lrun[4];
#pragma unroll
        for (int j = 0; j < 4; ++j) { mrun[j] = -3e38f; lrun[j] = 0.0f; }

        const int nkv = 2 * jt + 2;
        for (int it = 0; it < nkv; ++it) {
            const int kv0 = it * 32;
            __syncthreads();
            {
                const size_t rbase = base + (size_t)(kv0 + srow) * (3 * Dm);
                *(ushort8*)&Ks[srow][sc8] = *(const ushort8*)&qkv[rbase + Dm + sc8];
                ushort8 vvv = *(const ushort8*)&qkv[rbase + 2 * Dm + sc8];
#pragma unroll
                for (int jj = 0; jj < 8; ++jj) Vt[sc8 + jj][srow] = vvv[jj];
            }
            __syncthreads();

            f32x4 s[2] = {};
#pragma unroll
            for (int kh = 0; kh < 2; ++kh) {
#pragma unroll
                for (int n = 0; n < 2; ++n) {
                    bf16x8 bk = *(const bf16x8*)&Ks[n * 16 + lr][kh * 32 + lk];
                    s[n] = __builtin_amdgcn_mfma_f32_16x16x32_bf16(aq[kh], bk, s[n], 0, 0, 0);
                }
            }

            float scale[4];
#pragma unroll
            for (int j = 0; j < 4; ++j) {
                const int qrow = q0 + g * 4 + j;
                float v0 = (kv0 + lr      <= qrow) ? s[0][j] * 0.125f : -3e38f;
                float v1 = (kv0 + 16 + lr <= qrow) ? s[1][j] * 0.125f : -3e38f;
                float rm = fmaxf(v0, v1);
#pragma unroll
                for (int msk = 1; msk < 16; msk <<= 1)
                    rm = fmaxf(rm, __shfl_xor(rm, msk));
                float mnew = fmaxf(mrun[j], rm);
                scale[j] = __expf(mrun[j] - mnew);
                float p0 = __expf(v0 - mnew);
                float p1 = __expf(v1 - mnew);
                s[0][j] = p0; s[1][j] = p1;
                float rs = p0 + p1;
#pragma unroll
                for (int msk = 1; msk < 16; msk <<= 1)
                    rs += __shfl_xor(rs, msk);
                lrun[j] = lrun[j] * scale[j] + rs;
                mrun[j] = mnew;
            }

#pragma unroll
            for (int n = 0; n < 2; ++n)
#pragma unroll
                for (int j = 0; j < 4; ++j)
                    Ps[wv][g * 4 + j][n * 16 + lr] = f2b(s[n][j]);
            bf16x8 ap = *(const bf16x8*)&Ps[wv][lr][lk];

#pragma unroll
            for (int d = 0; d < 4; ++d) {
                f32x4 c = o[d];
#pragma unroll
                for (int j = 0; j < 4; ++j) c[j] *= scale[j];
                bf16x8 bv = *(const bf16x8*)&Vt[d * 16 + lr][lk];
                o[d] = __builtin_amdgcn_mfma_f32_16x16x32_bf16(ap, bv, c, 0, 0, 0);
            }
        }

#pragma unroll
        for (int d = 0; d < 4; ++d) {
#pragma unroll
            for (int j = 0; j < 4; ++j) {
                const int qrow = q0 + g * 4 + j;
                attn[(size_t)(b * Tn + qrow) * Dm + h * HDm + d * 16 + lr] =
                    f2b(o[d][j] / lrun[j]);
            }
        }
    }
}

// ---------------- host orchestration ---------------------------------------------
extern "C" void kernel_launch(void* const* d_in, const int* in_sizes, int n_in,
                              void* d_out, int out_size, void* d_ws, size_t ws_size,
                              hipStream_t stream)
{
    const int*  ids       = (const int*)d_in[0];
    const void* text_emb  = d_in[1];
    const void* pos_emb   = d_in[2];
    const void* qkv_w     = d_in[3];
    const void* qkv_b     = d_in[4];
    const void* out_w     = d_in[5];
    const void* out_b     = d_in[6];
    const void* ln1_w     = d_in[7];
    const void* ln1_b     = d_in[8];
    const void* ln2_w     = d_in[9];
    const void* ln2_b     = d_in[10];
    const void* w1        = d_in[11];
    const void* b1        = d_in[12];
    const void* w2        = d_in[13];
    const void* b2        = d_in[14];
    const void* lnf_w     = d_in[15];
    const void* lnf_b     = d_in[16];
    const void* lm_head_w = d_in[17];

    char* ws = (char*)d_ws;
    size_t used = 0;
    auto carve = [&](size_t bytes) { char* p = ws + used; used += (bytes + 15) & ~15ull; return p; };

    int*   flag = (int*)  carve(16);
    float* x    = (float*)carve((size_t)NT * Dm * 4);
    u16*   h    = (u16*)  carve((size_t)NT * Dm * 2);       // aliased by vt
    u16*   qkv  = (u16*)  carve((size_t)NT * 3 * Dm * 2);   // aliased by Pf[0..1]
    u16*   attn = (u16*)  carve((size_t)NT * Dm * 2);
    u16*   u    = (u16*)  carve((size_t)NT * DFF * 2);      // aliased by Pa[0..1]

    u16*   vt = h;
    float* Pf = (float*)qkv;
    float* Pa = (float*)u;

    const size_t nLM  = (size_t)Vn * Dm;
    const size_t nQKV = (size_t)Ln * 3 * Dm * Dm;
    const size_t nOUT = (size_t)Ln * Dm * Dm;
    const size_t nW1  = (size_t)Ln * DFF * Dm;
    const size_t nW2  = (size_t)Ln * Dm * DFF;

    u16* wsLM  = (u16*)carve(nLM * 2);
    size_t lm_used = used;
    u16* wsQKV = (u16*)carve(nQKV * 2);
    u16* wsOUT = (u16*)carve(nOUT * 2);
    u16* wsW1  = (u16*)carve(nW1 * 2);
    u16* wsW2  = (u16*)carve(nW2 * 2);
    size_t t2_used = used;

    const int tier = (ws_size >= t2_used) ? 2 : (ws_size >= lm_used ? 1 : 0);

    dim3 blk(256);

    sniff_k<<<1, blk, 0, stream>>>(text_emb, flag);

    if (tier >= 1)
        conv_k<<<nLM / 2048, blk, 0, stream>>>(lm_head_w, wsLM, flag);
    if (tier >= 2) {
        conv_k<<<nQKV / 2048, blk, 0, stream>>>(qkv_w, wsQKV, flag);
        conv_k<<<nOUT / 2048, blk, 0, stream>>>(out_w, wsOUT, flag);
        conv_k<<<nW1  / 2048, blk, 0, stream>>>(w1,    wsW1,  flag);
        conv_k<<<nW2  / 2048, blk, 0, stream>>>(w2,    wsW2,  flag);
    }

    embed_k<<<NT, blk, 0, stream>>>(ids, text_emb, pos_emb, x, flag);

    if (tier >= 2) {
        for (int l = 0; l < Ln; ++l) {
            size_t oQW = (size_t)l * 3 * Dm * Dm, oQB = (size_t)l * 3 * Dm;
            size_t oOW = (size_t)l * Dm * Dm,     oOB = (size_t)l * Dm;
            size_t oW1 = (size_t)l * DFF * Dm,    oB1 = (size_t)l * DFF;
            size_t oW2 = (size_t)l * Dm * DFF,    oB2 = (size_t)l * Dm;
            size_t oLN = (size_t)l * Dm;

            lnfuse_k<<<NT, blk, 0, stream>>>(x, Pf, (l == 0) ? 0 : 2,
                                             ln1_w, ln1_b, oLN, h, flag);
            gemm2p_k<0><<<16 * (3 * Dm / 128), blk, 0, stream>>>(
                h, qkv_w, oQW, wsQKV + oQW, qkv_b, oQB, qkv, nullptr, nullptr,
                flag, 3 * Dm, Dm, Dm, 1);
            vtrans_k<<<32 * 16, blk, 0, stream>>>(qkv, vt);
            fattn2_k<<<2048, dim3(64), 0, stream>>>(qkv, vt, attn);
            gemm2p_k<4><<<2 * 16 * (Dm / 128), blk, 0, stream>>>(
                attn, out_w, oOW, wsOUT + oOW, out_b, oOB, nullptr, nullptr, Pa,
                flag, Dm, Dm, Dm / 2, 2);
            lnfuse_k<<<NT, blk, 0, stream>>>(x, Pa, 2, ln2_w, ln2_b, oLN, h, flag);
            gemm2p_k<1><<<16 * (DFF / 128), blk, 0, stream>>>(
                h, w1, oW1, wsW1 + oW1, b1, oB1, u, nullptr, nullptr,
                flag, DFF, Dm, Dm, 1);
            gemm2p_k<4><<<2 * 16 * (Dm / 128), blk, 0, stream>>>(
                u, w2, oW2, wsW2 + oW2, b2, oB2, nullptr, nullptr, Pf,
                flag, Dm, DFF, DFF / 2, 2);
        }
        lnfuse_k<<<NT, blk, 0, stream>>>(x, Pf, 2, lnf_w, lnf_b, 0, h, flag);
        gemm3_k<3><<<8 * (Vn / 256), dim3(512), 0, stream>>>(
            h, lm_head_w, 0, wsLM, nullptr, 0, nullptr, d_out, flag, Vn, Dm);
    } else {
        for (int l = 0; l < Ln; ++l) {
            size_t oQW = (size_t)l * 3 * Dm * Dm, oQB = (size_t)l * 3 * Dm;
            size_t oOW = (size_t)l * Dm * Dm,     oOB = (size_t)l * Dm;
            size_t oW1 = (size_t)l * DFF * Dm,    oB1 = (size_t)l * DFF;
            size_t oW2 = (size_t)l * Dm * DFF,    oB2 = (size_t)l * Dm;
            size_t oLN = (size_t)l * Dm;

            ln_k<<<NT, blk, 0, stream>>>(x, ln1_w, ln1_b, oLN, h, flag);
            gemm_k<0><<<dim3(3 * Dm / 128, NT / 128), blk, 0, stream>>>(
                h, qkv_w, oQW, qkv_b, oQB, qkv, nullptr, nullptr, flag, NT, 3 * Dm, Dm);
            fattn_k<<<2 * Hn * 8, blk, 0, stream>>>(qkv, attn);
            gemm_k<2><<<dim3(Dm / 128, NT / 128), blk, 0, stream>>>(
                attn, out_w, oOW, out_b, oOB, nullptr, x, nullptr, flag, NT, Dm, Dm);
            ln_k<<<NT, blk, 0, stream>>>(x, ln2_w, ln2_b, oLN, h, flag);
            gemm_k<1><<<dim3(DFF / 128, NT / 128), blk, 0, stream>>>(
                h, w1, oW1, b1, oB1, u, nullptr, nullptr, flag, NT, DFF, Dm);
            gemm_k<2><<<dim3(Dm / 128, NT / 128), blk, 0, stream>>>(
                u, w2, oW2, b2, oB2, nullptr, x, nullptr, flag, NT, Dm, DFF);
        }
        ln_k<<<NT, blk, 0, stream>>>(x, lnf_w, lnf_b, 0, h, flag);
        if (tier == 1)
            gemm3_k<3><<<8 * (Vn / 256), dim3(512), 0, stream>>>(
                h, lm_head_w, 0, wsLM, nullptr, 0, nullptr, d_out, flag, Vn, Dm);
        else
            gemm_k<3><<<dim3(Vn / 128, NT / 128), blk, 0, stream>>>(
                h, lm_head_w, 0, nullptr, 0, nullptr, nullptr, d_out, flag, NT, Vn, Dm);
    }
}